// Round 1
// baseline (762.166 us; speedup 1.0000x reference)
//
#include <hip/hip_runtime.h>
#include <hip/hip_bf16.h>

typedef __attribute__((ext_vector_type(8))) __bf16 bf16x8;
typedef __attribute__((ext_vector_type(4))) float floatx4;

constexpr int N_TOK = 4096;   // B*T
constexpr int DDIM  = 1024;
constexpr int FDIM  = 4096;
constexpr int NEXP  = 8;
constexpr int NSLOT = 2 * N_TOK; // 8192 assignments (top-2)
constexpr int BM_T  = 256;       // M tile
constexpr int MAXT  = NSLOT / BM_T + NEXP - 1; // 39 max M-tiles at BM=256
constexpr int KSPLIT = 2;        // down-GEMM K split

static __device__ __forceinline__ unsigned short f2bf(float f) {
    union { __hip_bfloat16 h; unsigned short u; } v;
    v.h = __float2bfloat16(f);
    return v.u;
}

// async 16B global->LDS DMA. LDS dest = wave-uniform base + lane*16 (m104/m108).
static __device__ __forceinline__ void gl2lds16(const unsigned short* g, unsigned short* l) {
    __builtin_amdgcn_global_load_lds(
        (__attribute__((address_space(1))) void*)g,
        (__attribute__((address_space(3))) void*)l,
        16, 0, 0);
}

// ---------------- fused W1+W2 fp32 -> bf16 cast (+ counts init) ----------------
__global__ void castW_kernel(const float* __restrict__ W1, const float* __restrict__ W2,
                             unsigned short* __restrict__ w1b, unsigned short* __restrict__ w2b,
                             int* __restrict__ counts) {
    constexpr int HALF = NEXP * FDIM * DDIM / 4; // float4 groups per tensor
    int i = blockIdx.x * 256 + threadIdx.x;
    const float* s; unsigned short* d; int j;
    if (i < HALF) { s = W1; d = w1b; j = i; }
    else          { s = W2; d = w2b; j = i - HALF; }
    float4 v = *(const float4*)(s + (size_t)j * 4);
    ushort4 o;
    o.x = f2bf(v.x); o.y = f2bf(v.y); o.z = f2bf(v.z); o.w = f2bf(v.w);
    *(ushort4*)(d + (size_t)j * 4) = o;
    if (blockIdx.x == 0 && threadIdx.x < NEXP) counts[threadIdx.x] = 0;
}

// ---------------- router: logits -> top2 -> weights; also emits xb ----------------
__global__ void router_kernel(const float* __restrict__ x, const float* __restrict__ Wr,
                              unsigned short* __restrict__ xb,
                              int* __restrict__ te, float* __restrict__ tw,
                              int* __restrict__ counts) {
    __shared__ float wr[NEXP * DDIM]; // 32 KB
    const int tid = threadIdx.x;
    for (int i = tid; i < NEXP * DDIM; i += 256) wr[i] = Wr[i];
    __syncthreads();
    const int wave = tid >> 6, lane = tid & 63;
    const int t = blockIdx.x * 4 + wave;

    float xr[16];
    const float* xp = x + (size_t)t * DDIM;
    #pragma unroll
    for (int i = 0; i < 16; i++) xr[i] = xp[lane + 64 * i];

    // fused x -> bf16 cast (same row already in registers)
    unsigned short* xbp = xb + (size_t)t * DDIM;
    #pragma unroll
    for (int i = 0; i < 16; i++) xbp[lane + 64 * i] = f2bf(xr[i]);

    float logit[NEXP];
    #pragma unroll
    for (int e = 0; e < NEXP; e++) {
        float s = 0.f;
        #pragma unroll
        for (int i = 0; i < 16; i++) s += xr[i] * wr[e * DDIM + lane + 64 * i];
        #pragma unroll
        for (int off = 32; off > 0; off >>= 1) s += __shfl_xor(s, off, 64);
        logit[e] = s;
    }
    if (lane == 0) {
        int i0 = 0; float l0 = logit[0];
        #pragma unroll
        for (int e = 1; e < NEXP; e++) if (logit[e] > l0) { l0 = logit[e]; i0 = e; }
        int i1 = -1; float l1 = -3.0e38f;
        #pragma unroll
        for (int e = 0; e < NEXP; e++) if (e != i0 && logit[e] > l1) { l1 = logit[e]; i1 = e; }
        float p1 = expf(l1 - l0);
        float w0 = 1.f / (1.f + p1);
        float w1 = p1 * w0;
        te[t * 2] = i0; te[t * 2 + 1] = i1;
        tw[t * 2] = w0; tw[t * 2 + 1] = w1;
        atomicAdd(&counts[i0], 1);
        atomicAdd(&counts[i1], 1);
    }
}

// ---------------- fused scan + tile table + scatter (single block) ----------------
__global__ void scan_scatter_kernel(const int* __restrict__ counts,
                                    const int* __restrict__ te, const float* __restrict__ tw,
                                    int* __restrict__ offsets, int* __restrict__ tile_em,
                                    int* __restrict__ ntile,
                                    int* __restrict__ rowid, float* __restrict__ gate,
                                    int* __restrict__ tok2slot) {
    __shared__ int soff[NEXP];
    __shared__ int scur[NEXP];
    const int tid = threadIdx.x;
    if (tid == 0) {
        int acc = 0, nt = 0;
        for (int e = 0; e < NEXP; e++) {
            offsets[e] = acc; soff[e] = acc;
            for (int m0 = 0; m0 < counts[e]; m0 += BM_T)
                tile_em[nt++] = (e << 16) | (m0 >> 8);
            acc += counts[e];
        }
        offsets[NEXP] = acc;
        ntile[0] = nt;
        for (int i = nt; i < MAXT; i++) tile_em[i] = 0;
    }
    if (tid < NEXP) scur[tid] = 0;
    __syncthreads();
    for (int t = tid; t < N_TOK; t += 256) {
        #pragma unroll
        for (int k = 0; k < 2; k++) {
            int e = te[t * 2 + k];
            int pos = atomicAdd(&scur[e], 1);
            int slot = soff[e] + pos;
            rowid[slot] = t;
            gate[slot] = tw[t * 2 + k];
            tok2slot[t * 2 + k] = slot;
        }
    }
}

// ---------------- grouped GEMM: 256-row tiles, BK=64, 8 waves, 2-phase dbuf ----------------
// UP:  A = xb gathered rows [cnt x 1024] @ W1^T -> gelu -> H bf16   (BM=256, BN=256)
// DOWN:A = H rows [cnt x 4096] @ W2^T (K-split) -> gate* -> Y slab  (BM=256, BN=128)
// Pipeline (T3-minimum, m230/m248): stage(next buf) BEFORE compute(cur buf); the single
// __syncthreads (implicit vmcnt(0)+lgkmcnt(0)) drains loads that overlapped the MFMAs.
// LDS swizzle via pre-swizzled gl2lds *source* col + XOR'd ds_read col (rule #21):
//   LDS[row][c] = global[row][c ^ ((row&7)*8 shorts)] -> ds_read_b128 is <=2-way (free).
template <bool UP>
__global__ __launch_bounds__(512)
void ffn_gemm(const unsigned short* __restrict__ A,
              const unsigned short* __restrict__ Wb,
              unsigned short* __restrict__ Hout,
              float* __restrict__ Y,
              const int* __restrict__ rowid,
              const float* __restrict__ gate,
              const int* __restrict__ offsets,
              const int* __restrict__ tile_em,
              const int* __restrict__ ntile) {
    constexpr int BM = 256;
    constexpr int BN = UP ? 256 : 128;
    constexpr int BK = 64;
    constexpr int NOUT = UP ? FDIM : DDIM;
    constexpr int KDIM = UP ? DDIM : FDIM;
    constexpr int NN   = NOUT / BN;                  // 16 / 8
    constexpr int KLEN = UP ? DDIM : (FDIM / KSPLIT); // 1024 / 2048
    constexpr int KT   = KLEN / BK;                  // 16 / 32
    constexpr int WN_W = UP ? 4 : 2;                 // waves across N (8 waves total)
    constexpr int MREP = UP ? 8 : 4;                 // 16-row frags per wave in M
    constexpr int NREP = 4;                          // 16-col frags per wave in N
    constexpr int AINST = BM / 64;                   // gl2lds instrs per wave for A (4)
    constexpr int BINST = BN / 64;                   // for B (4 / 2)
    constexpr int ASTRIDE = BM * BK;                 // shorts per A buffer
    constexpr int BSTRIDE = BN * BK;

    // bijective XCD-chunked swizzle (m204): XCD k gets a contiguous id chunk.
    const int nwg = NN * MAXT * (UP ? 1 : KSPLIT);   // == gridDim.x
    const int orig = blockIdx.x;
    const int xcd = orig & 7, idx = orig >> 3;
    const int q = nwg >> 3, r = nwg & 7;
    const int id = (xcd < r ? xcd * (q + 1) : r * (q + 1) + (xcd - r) * q) + idx;

    const int n0 = (id % NN) * BN;                   // n fastest: neighbors share A tile
    const int bt = (id / NN) % MAXT;
    const int ks = UP ? 0 : (id / (NN * MAXT));
    if (bt >= ntile[0]) return;
    const int em = tile_em[bt];
    const int e  = em >> 16;
    const int m0 = (em & 0xffff) << 8;
    const int seg = offsets[e];
    const int cnt = offsets[e + 1] - seg;
    const int kbase = ks * KLEN;

    __shared__ __align__(16) unsigned short As[2 * ASTRIDE]; // 64 KB
    __shared__ __align__(16) unsigned short Bs[2 * BSTRIDE]; // 64 / 32 KB

    const int tid  = threadIdx.x;
    const int lane = tid & 63;
    const int wave = tid >> 6;
    const int lrow = lane >> 3;                      // 0..7: row within 8-row DMA group
    const int scol = ((lane & 7) ^ lrow) * 8;        // inverse-swizzled SOURCE col (shorts)

    // global source pointers (advance by BK per staged tile)
    const unsigned short* ag[AINST];
    #pragma unroll
    for (int j = 0; j < AINST; j++) {
        int arow = wave * (BM / 8) + j * 8 + lrow;
        int slot = seg + m0 + arow;
        if (slot >= NSLOT) slot = NSLOT - 1;         // clamp; write-guarded later
        if (UP) { int t = rowid[slot]; ag[j] = A + (size_t)t * DDIM + kbase + scol; }
        else    { ag[j] = A + (size_t)slot * FDIM + kbase + scol; }
    }
    const unsigned short* bg[BINST];
    #pragma unroll
    for (int j = 0; j < BINST; j++) {
        int brow = wave * (BN / 8) + j * 8 + lrow;
        bg[j] = Wb + ((size_t)e * NOUT + n0 + brow) * KDIM + kbase + scol;
    }
    // linear LDS dests (gl2lds requirement): base + lane*16B
    unsigned short* asl[AINST];
    unsigned short* bsl[BINST];
    #pragma unroll
    for (int j = 0; j < AINST; j++)
        asl[j] = &As[(wave * (BM / 8) + j * 8) * BK] + lane * 8;
    #pragma unroll
    for (int j = 0; j < BINST; j++)
        bsl[j] = &Bs[(wave * (BN / 8) + j * 8) * BK] + lane * 8;

    auto stage = [&](int b) {
        #pragma unroll
        for (int j = 0; j < AINST; j++) { gl2lds16(ag[j], asl[j] + b * ASTRIDE); ag[j] += BK; }
        #pragma unroll
        for (int j = 0; j < BINST; j++) { gl2lds16(bg[j], bsl[j] + b * BSTRIDE); bg[j] += BK; }
    };

    const int frow = lane & 15;
    const int quad = lane >> 4;
    const int wm = (wave / WN_W) * (MREP * 16);
    const int wn = (wave % WN_W) * 64;
    const int sxor = (frow & 7) << 3;                // read-side swizzle (shorts)

    floatx4 acc[MREP][NREP];
    #pragma unroll
    for (int i = 0; i < MREP; i++)
        #pragma unroll
        for (int j = 0; j < NREP; j++)
            acc[i][j] = (floatx4){0.f, 0.f, 0.f, 0.f};

    stage(0);
    __syncthreads();                                 // drain prologue DMA
    for (int kt = 0; kt < KT; kt++) {
        if (kt + 1 < KT) stage((kt + 1) & 1);        // issue next tile BEFORE compute
        const unsigned short* Ab = &As[(kt & 1) * ASTRIDE];
        const unsigned short* Bb = &Bs[(kt & 1) * BSTRIDE];
        #pragma unroll
        for (int h = 0; h < 2; h++) {                // two k=32 substeps of the BK=64 tile
            const int cs = (h * 32 + quad * 8) ^ sxor;
            bf16x8 av[MREP], bv[NREP];
            #pragma unroll
            for (int i = 0; i < MREP; i++)
                av[i] = *(const bf16x8*)&Ab[(wm + i * 16 + frow) * BK + cs];
            #pragma unroll
            for (int j = 0; j < NREP; j++)
                bv[j] = *(const bf16x8*)&Bb[(wn + j * 16 + frow) * BK + cs];
            #pragma unroll
            for (int i = 0; i < MREP; i++)
                #pragma unroll
                for (int j = 0; j < NREP; j++)
                    acc[i][j] = __builtin_amdgcn_mfma_f32_16x16x32_bf16(av[i], bv[j], acc[i][j], 0, 0, 0);
        }
        __syncthreads();                             // drains this iter's DMA (overlapped above)
    }

    // epilogue: C/D layout col=lane&15, row=quad*4+reg (m89/m91-verified)
    #pragma unroll
    for (int mt = 0; mt < MREP; mt++) {
        #pragma unroll
        for (int rr = 0; rr < 4; rr++) {
            int mloc = m0 + wm + mt * 16 + quad * 4 + rr;
            if (mloc >= cnt) continue;               // write-guard
            int slot = seg + mloc;
            if (UP) {
                #pragma unroll
                for (int nt = 0; nt < NREP; nt++) {
                    int n = n0 + wn + nt * 16 + frow;
                    float v = acc[mt][nt][rr];
                    float g = 0.5f * v * (1.0f + erff(v * 0.70710678118654752f)); // exact gelu
                    Hout[(size_t)slot * FDIM + n] = f2bf(g);
                }
            } else {
                float gw = gate[slot];
                #pragma unroll
                for (int nt = 0; nt < NREP; nt++) {
                    int n = n0 + wn + nt * 16 + frow;
                    Y[((size_t)ks * NSLOT + slot) * DDIM + n] = gw * acc[mt][nt][rr];
                }
            }
        }
    }
}

// ---------------- combine: out[t] = sum over ks slabs of Y[slot0]+Y[slot1] ----------------
__global__ void combine_kernel(const float* __restrict__ Y, const int* __restrict__ tok2slot,
                               float* __restrict__ out) {
    int idx = blockIdx.x * 256 + threadIdx.x;
    int t = idx >> 8;
    int c = (idx & 255) * 4;
    int s0 = tok2slot[t * 2], s1 = tok2slot[t * 2 + 1];
    float4 r = make_float4(0.f, 0.f, 0.f, 0.f);
    #pragma unroll
    for (int ks = 0; ks < KSPLIT; ks++) {
        float4 a = *(const float4*)(Y + ((size_t)ks * NSLOT + s0) * DDIM + c);
        float4 b = *(const float4*)(Y + ((size_t)ks * NSLOT + s1) * DDIM + c);
        r.x += a.x + b.x; r.y += a.y + b.y; r.z += a.z + b.z; r.w += a.w + b.w;
    }
    *(float4*)(out + (size_t)t * DDIM + c) = r;
}

extern "C" void kernel_launch(void* const* d_in, const int* in_sizes, int n_in,
                              void* d_out, int out_size, void* d_ws, size_t ws_size,
                              hipStream_t stream) {
    const float* x  = (const float*)d_in[0];
    const float* Wr = (const float*)d_in[1];
    const float* W1 = (const float*)d_in[2];
    const float* W2 = (const float*)d_in[3];
    float* out = (float*)d_out;

    char* ws = (char*)d_ws;
    size_t off = 0;
    auto alloc = [&](size_t bytes) -> char* {
        char* p = ws + off;
        off = (off + bytes + 255) & ~(size_t)255;
        return p;
    };
    unsigned short* xb   = (unsigned short*)alloc((size_t)N_TOK * DDIM * 2);
    unsigned short* H    = (unsigned short*)alloc((size_t)NSLOT * FDIM * 2);
    float* Yb      = (float*)alloc((size_t)KSPLIT * NSLOT * DDIM * 4);
    int*   rowid   = (int*)alloc(NSLOT * 4);
    float* gatew   = (float*)alloc(NSLOT * 4);
    int*   te      = (int*)alloc(NSLOT * 4);
    float* tw      = (float*)alloc(NSLOT * 4);
    int*   t2s     = (int*)alloc(NSLOT * 4);
    int*   counts  = (int*)alloc(64);
    int*   offsets = (int*)alloc(64);
    int*   tile_em = (int*)alloc(MAXT * 4);
    int*   ntile   = (int*)alloc(64);
    unsigned short* w1b = (unsigned short*)alloc((size_t)NEXP * FDIM * DDIM * 2);
    unsigned short* w2b = (unsigned short*)alloc((size_t)NEXP * DDIM * FDIM * 2);
    (void)ws_size;

    constexpr int GRID_UP = (FDIM / 256) * MAXT;           // 624 blocks
    constexpr int GRID_DN = (DDIM / 128) * MAXT * KSPLIT;  // 624 blocks

    castW_kernel<<<2 * NEXP * FDIM * DDIM / 4 / 256, 256, 0, stream>>>(W1, W2, w1b, w2b, counts);
    router_kernel<<<N_TOK / 4, 256, 0, stream>>>(x, Wr, xb, te, tw, counts);
    scan_scatter_kernel<<<1, 256, 0, stream>>>(counts, te, tw, offsets, tile_em, ntile,
                                               rowid, gatew, t2s);
    ffn_gemm<true ><<<GRID_UP, 512, 0, stream>>>(xb, w1b, H, Yb, rowid, gatew,
                                                 offsets, tile_em, ntile);
    ffn_gemm<false><<<GRID_DN, 512, 0, stream>>>(H, w2b, H, Yb, rowid, gatew,
                                                 offsets, tile_em, ntile);
    combine_kernel<<<N_TOK, 256, 0, stream>>>(Yb, t2s, out);
}

// Round 2
// 683.881 us; speedup vs baseline: 1.1145x; 1.1145x over previous
//
#include <hip/hip_runtime.h>
#include <hip/hip_bf16.h>

typedef __attribute__((ext_vector_type(8))) __bf16 bf16x8;
typedef __attribute__((ext_vector_type(4))) float floatx4;

constexpr int N_TOK = 4096;   // B*T
constexpr int DDIM  = 1024;
constexpr int FDIM  = 4096;
constexpr int NEXP  = 8;
constexpr int NSLOT = 2 * N_TOK; // 8192 assignments (top-2)
constexpr int BM_T  = 256;       // M tile
constexpr int MAXT  = NSLOT / BM_T + NEXP - 1; // 39 max M-tiles at BM=256
constexpr int KSPLIT = 2;        // down-GEMM K split

static __device__ __forceinline__ unsigned short f2bf(float f) {
    union { __hip_bfloat16 h; unsigned short u; } v;
    v.h = __float2bfloat16(f);
    return v.u;
}

// async 16B global->LDS DMA. LDS dest = wave-uniform base + lane*16 (m104/m108).
static __device__ __forceinline__ void gl2lds16(const unsigned short* g, unsigned short* l) {
    __builtin_amdgcn_global_load_lds(
        (__attribute__((address_space(1))) void*)g,
        (__attribute__((address_space(3))) void*)l,
        16, 0, 0);
}

// ---------------- fused W1+W2 fp32 -> bf16 cast (+ counts init) ----------------
__global__ void castW_kernel(const float* __restrict__ W1, const float* __restrict__ W2,
                             unsigned short* __restrict__ w1b, unsigned short* __restrict__ w2b,
                             int* __restrict__ counts) {
    constexpr int HALF = NEXP * FDIM * DDIM / 4; // float4 groups per tensor
    int i = blockIdx.x * 256 + threadIdx.x;
    const float* s; unsigned short* d; int j;
    if (i < HALF) { s = W1; d = w1b; j = i; }
    else          { s = W2; d = w2b; j = i - HALF; }
    float4 v = *(const float4*)(s + (size_t)j * 4);
    ushort4 o;
    o.x = f2bf(v.x); o.y = f2bf(v.y); o.z = f2bf(v.z); o.w = f2bf(v.w);
    *(ushort4*)(d + (size_t)j * 4) = o;
    if (blockIdx.x == 0 && threadIdx.x < NEXP) counts[threadIdx.x] = 0;
}

// ---------------- router: logits -> top2 -> weights; also emits xb ----------------
__global__ void router_kernel(const float* __restrict__ x, const float* __restrict__ Wr,
                              unsigned short* __restrict__ xb,
                              int* __restrict__ te, float* __restrict__ tw,
                              int* __restrict__ counts) {
    __shared__ float wr[NEXP * DDIM]; // 32 KB
    const int tid = threadIdx.x;
    for (int i = tid; i < NEXP * DDIM; i += 256) wr[i] = Wr[i];
    __syncthreads();
    const int wave = tid >> 6, lane = tid & 63;
    const int t = blockIdx.x * 4 + wave;

    float xr[16];
    const float* xp = x + (size_t)t * DDIM;
    #pragma unroll
    for (int i = 0; i < 16; i++) xr[i] = xp[lane + 64 * i];

    // fused x -> bf16 cast (same row already in registers)
    unsigned short* xbp = xb + (size_t)t * DDIM;
    #pragma unroll
    for (int i = 0; i < 16; i++) xbp[lane + 64 * i] = f2bf(xr[i]);

    float logit[NEXP];
    #pragma unroll
    for (int e = 0; e < NEXP; e++) {
        float s = 0.f;
        #pragma unroll
        for (int i = 0; i < 16; i++) s += xr[i] * wr[e * DDIM + lane + 64 * i];
        #pragma unroll
        for (int off = 32; off > 0; off >>= 1) s += __shfl_xor(s, off, 64);
        logit[e] = s;
    }
    if (lane == 0) {
        int i0 = 0; float l0 = logit[0];
        #pragma unroll
        for (int e = 1; e < NEXP; e++) if (logit[e] > l0) { l0 = logit[e]; i0 = e; }
        int i1 = -1; float l1 = -3.0e38f;
        #pragma unroll
        for (int e = 0; e < NEXP; e++) if (e != i0 && logit[e] > l1) { l1 = logit[e]; i1 = e; }
        float p1 = expf(l1 - l0);
        float w0 = 1.f / (1.f + p1);
        float w1 = p1 * w0;
        te[t * 2] = i0; te[t * 2 + 1] = i1;
        tw[t * 2] = w0; tw[t * 2 + 1] = w1;
        atomicAdd(&counts[i0], 1);
        atomicAdd(&counts[i1], 1);
    }
}

// ---------------- fused scan + tile table + scatter (single block) ----------------
__global__ void scan_scatter_kernel(const int* __restrict__ counts,
                                    const int* __restrict__ te, const float* __restrict__ tw,
                                    int* __restrict__ offsets, int* __restrict__ tile_em,
                                    int* __restrict__ ntile,
                                    int* __restrict__ rowid, float* __restrict__ gate,
                                    int* __restrict__ tok2slot) {
    __shared__ int soff[NEXP];
    __shared__ int scur[NEXP];
    const int tid = threadIdx.x;
    if (tid == 0) {
        int acc = 0, nt = 0;
        for (int e = 0; e < NEXP; e++) {
            offsets[e] = acc; soff[e] = acc;
            for (int m0 = 0; m0 < counts[e]; m0 += BM_T)
                tile_em[nt++] = (e << 16) | (m0 >> 8);
            acc += counts[e];
        }
        offsets[NEXP] = acc;
        ntile[0] = nt;
        for (int i = nt; i < MAXT; i++) tile_em[i] = 0;
    }
    if (tid < NEXP) scur[tid] = 0;
    __syncthreads();
    for (int t = tid; t < N_TOK; t += 256) {
        #pragma unroll
        for (int k = 0; k < 2; k++) {
            int e = te[t * 2 + k];
            int pos = atomicAdd(&scur[e], 1);
            int slot = soff[e] + pos;
            rowid[slot] = t;
            gate[slot] = tw[t * 2 + k];
            tok2slot[t * 2 + k] = slot;
        }
    }
}

// ---------------- grouped GEMM: BM=256 BN=128 BK=32, 8 waves (4Mx2N), dbuf ----------------
// Round-2 geometry: 64x64 wave tile -> acc 64 + operands 32 regs fits 4 waves/SIMD
// under __launch_bounds__(512,4); LDS 48 KB -> 2 blocks/CU = 16 waves/CU of TLP
// (round-1's 1 blk/CU exposed the full drain latency; round-0 proved TLP hides it).
// Keeps: prefetch-next-before-compute, XOR source/read swizzle (0 conflicts),
// bijective XCD chunking (FETCH at compulsory traffic).
template <bool UP>
__global__ __launch_bounds__(512, 4)
void ffn_gemm(const unsigned short* __restrict__ A,
              const unsigned short* __restrict__ Wb,
              unsigned short* __restrict__ Hout,
              float* __restrict__ Y,
              const int* __restrict__ rowid,
              const float* __restrict__ gate,
              const int* __restrict__ offsets,
              const int* __restrict__ tile_em,
              const int* __restrict__ ntile) {
    constexpr int BM = 256, BN = 128, BK = 32;
    constexpr int NOUT = UP ? FDIM : DDIM;
    constexpr int KDIM = UP ? DDIM : FDIM;
    constexpr int NN   = NOUT / BN;                   // 32 / 8
    constexpr int KLEN = UP ? DDIM : (FDIM / KSPLIT); // 1024 / 2048
    constexpr int KT   = KLEN / BK;                   // 32 / 64
    constexpr int MREP = 4, NREP = 4;                 // 64x64 wave tile
    constexpr int ASTRIDE = BM * BK;                  // 8192 shorts = 16 KB / buffer
    constexpr int BSTRIDE = BN * BK;                  // 4096 shorts =  8 KB / buffer

    // bijective XCD-chunked swizzle (m204)
    const int nwg = NN * MAXT * (UP ? 1 : KSPLIT);    // == gridDim.x
    const int orig = blockIdx.x;
    const int xcd = orig & 7, idx = orig >> 3;
    const int qq = nwg >> 3, rr8 = nwg & 7;
    const int id = (xcd < rr8 ? xcd * (qq + 1) : rr8 * (qq + 1) + (xcd - rr8) * qq) + idx;

    const int n0 = (id % NN) * BN;                    // n fastest: neighbors share A tile
    const int bt = (id / NN) % MAXT;
    const int ks = UP ? 0 : (id / (NN * MAXT));
    if (bt >= ntile[0]) return;
    const int em = tile_em[bt];
    const int e  = em >> 16;
    const int m0 = (em & 0xffff) << 8;
    const int seg = offsets[e];
    const int cnt = offsets[e + 1] - seg;
    const int kbase = ks * KLEN;

    __shared__ __align__(16) unsigned short As[2 * ASTRIDE]; // 32 KB
    __shared__ __align__(16) unsigned short Bs[2 * BSTRIDE]; // 16 KB

    const int tid  = threadIdx.x;
    const int lane = tid & 63;
    const int wave = tid >> 6;
    const int lrow = lane >> 2;                       // 0..15: row within 16-row DMA group
    const int chunk = lane & 3;                       // 16B chunk within 64B row
    const int scol = (chunk ^ (lrow & 3)) * 8;        // inverse-swizzled SOURCE col (shorts)

    // global source pointers (advance by BK shorts per staged tile)
    const unsigned short* ag[2];
    #pragma unroll
    for (int j = 0; j < 2; j++) {
        int arow = wave * 32 + j * 16 + lrow;
        int slot = seg + m0 + arow;
        if (slot >= NSLOT) slot = NSLOT - 1;          // clamp; write-guarded later
        if (UP) { int t = rowid[slot]; ag[j] = A + (size_t)t * DDIM + kbase + scol; }
        else    { ag[j] = A + (size_t)slot * FDIM + kbase + scol; }
    }
    const unsigned short* bg0 =
        Wb + ((size_t)e * NOUT + n0 + wave * 16 + lrow) * KDIM + kbase + scol;

    // linear LDS dests (gl2lds requirement): base + lane*16B
    unsigned short* asl[2];
    #pragma unroll
    for (int j = 0; j < 2; j++)
        asl[j] = &As[(wave * 32 + j * 16) * BK] + lane * 8;
    unsigned short* bsl0 = &Bs[(wave * 16) * BK] + lane * 8;

    auto stage = [&](int b) {
        gl2lds16(ag[0], asl[0] + b * ASTRIDE); ag[0] += BK;
        gl2lds16(ag[1], asl[1] + b * ASTRIDE); ag[1] += BK;
        gl2lds16(bg0,   bsl0   + b * BSTRIDE); bg0   += BK;
    };

    const int frow = lane & 15;
    const int quad = lane >> 4;
    const int wm = (wave >> 1) * 64;                  // 4 wave-rows
    const int wn = (wave & 1) * 64;                   // 2 wave-cols
    const int cs = ((quad ^ (frow & 3)) * 8);         // read-side swizzle (shorts)

    floatx4 acc[MREP][NREP];
    #pragma unroll
    for (int i = 0; i < MREP; i++)
        #pragma unroll
        for (int j = 0; j < NREP; j++)
            acc[i][j] = (floatx4){0.f, 0.f, 0.f, 0.f};

    stage(0);
    __syncthreads();                                  // drain prologue DMA
    for (int kt = 0; kt < KT; kt++) {
        if (kt + 1 < KT) stage((kt + 1) & 1);         // issue next tile BEFORE compute
        const unsigned short* Ab = &As[(kt & 1) * ASTRIDE];
        const unsigned short* Bb = &Bs[(kt & 1) * BSTRIDE];
        bf16x8 av[MREP], bv[NREP];
        #pragma unroll
        for (int i = 0; i < MREP; i++)
            av[i] = *(const bf16x8*)&Ab[(wm + i * 16 + frow) * BK + cs];
        #pragma unroll
        for (int j = 0; j < NREP; j++)
            bv[j] = *(const bf16x8*)&Bb[(wn + j * 16 + frow) * BK + cs];
        #pragma unroll
        for (int i = 0; i < MREP; i++)
            #pragma unroll
            for (int j = 0; j < NREP; j++)
                acc[i][j] = __builtin_amdgcn_mfma_f32_16x16x32_bf16(av[i], bv[j], acc[i][j], 0, 0, 0);
        __syncthreads();                              // drains this iter's DMA (overlapped above)
    }

    // epilogue: C/D layout col=lane&15, row=quad*4+reg (m89/m91-verified)
    #pragma unroll
    for (int mt = 0; mt < MREP; mt++) {
        #pragma unroll
        for (int rg = 0; rg < 4; rg++) {
            int mloc = m0 + wm + mt * 16 + quad * 4 + rg;
            if (mloc >= cnt) continue;                // write-guard
            int slot = seg + mloc;
            if (UP) {
                #pragma unroll
                for (int nt = 0; nt < NREP; nt++) {
                    int n = n0 + wn + nt * 16 + frow;
                    float v = acc[mt][nt][rg];
                    float g = 0.5f * v * (1.0f + erff(v * 0.70710678118654752f)); // exact gelu
                    Hout[(size_t)slot * FDIM + n] = f2bf(g);
                }
            } else {
                float gw = gate[slot];
                #pragma unroll
                for (int nt = 0; nt < NREP; nt++) {
                    int n = n0 + wn + nt * 16 + frow;
                    Y[((size_t)ks * NSLOT + slot) * DDIM + n] = gw * acc[mt][nt][rg];
                }
            }
        }
    }
}

// ---------------- combine: out[t] = sum over ks slabs of Y[slot0]+Y[slot1] ----------------
__global__ void combine_kernel(const float* __restrict__ Y, const int* __restrict__ tok2slot,
                               float* __restrict__ out) {
    int idx = blockIdx.x * 256 + threadIdx.x;
    int t = idx >> 8;
    int c = (idx & 255) * 4;
    int s0 = tok2slot[t * 2], s1 = tok2slot[t * 2 + 1];
    float4 r = make_float4(0.f, 0.f, 0.f, 0.f);
    #pragma unroll
    for (int ks = 0; ks < KSPLIT; ks++) {
        float4 a = *(const float4*)(Y + ((size_t)ks * NSLOT + s0) * DDIM + c);
        float4 b = *(const float4*)(Y + ((size_t)ks * NSLOT + s1) * DDIM + c);
        r.x += a.x + b.x; r.y += a.y + b.y; r.z += a.z + b.z; r.w += a.w + b.w;
    }
    *(float4*)(out + (size_t)t * DDIM + c) = r;
}

extern "C" void kernel_launch(void* const* d_in, const int* in_sizes, int n_in,
                              void* d_out, int out_size, void* d_ws, size_t ws_size,
                              hipStream_t stream) {
    const float* x  = (const float*)d_in[0];
    const float* Wr = (const float*)d_in[1];
    const float* W1 = (const float*)d_in[2];
    const float* W2 = (const float*)d_in[3];
    float* out = (float*)d_out;

    char* ws = (char*)d_ws;
    size_t off = 0;
    auto alloc = [&](size_t bytes) -> char* {
        char* p = ws + off;
        off = (off + bytes + 255) & ~(size_t)255;
        return p;
    };
    unsigned short* xb   = (unsigned short*)alloc((size_t)N_TOK * DDIM * 2);
    unsigned short* H    = (unsigned short*)alloc((size_t)NSLOT * FDIM * 2);
    float* Yb      = (float*)alloc((size_t)KSPLIT * NSLOT * DDIM * 4);
    int*   rowid   = (int*)alloc(NSLOT * 4);
    float* gatew   = (float*)alloc(NSLOT * 4);
    int*   te      = (int*)alloc(NSLOT * 4);
    float* tw      = (float*)alloc(NSLOT * 4);
    int*   t2s     = (int*)alloc(NSLOT * 4);
    int*   counts  = (int*)alloc(64);
    int*   offsets = (int*)alloc(64);
    int*   tile_em = (int*)alloc(MAXT * 4);
    int*   ntile   = (int*)alloc(64);
    unsigned short* w1b = (unsigned short*)alloc((size_t)NEXP * FDIM * DDIM * 2);
    unsigned short* w2b = (unsigned short*)alloc((size_t)NEXP * DDIM * FDIM * 2);
    (void)ws_size;

    constexpr int GRID_UP = (FDIM / 128) * MAXT;           // 1248 blocks
    constexpr int GRID_DN = (DDIM / 128) * MAXT * KSPLIT;  // 624 blocks

    castW_kernel<<<2 * NEXP * FDIM * DDIM / 4 / 256, 256, 0, stream>>>(W1, W2, w1b, w2b, counts);
    router_kernel<<<N_TOK / 4, 256, 0, stream>>>(x, Wr, xb, te, tw, counts);
    scan_scatter_kernel<<<1, 256, 0, stream>>>(counts, te, tw, offsets, tile_em, ntile,
                                               rowid, gatew, t2s);
    ffn_gemm<true ><<<GRID_UP, 512, 0, stream>>>(xb, w1b, H, Yb, rowid, gatew,
                                                 offsets, tile_em, ntile);
    ffn_gemm<false><<<GRID_DN, 512, 0, stream>>>(H, w2b, H, Yb, rowid, gatew,
                                                 offsets, tile_em, ntile);
    combine_kernel<<<N_TOK, 256, 0, stream>>>(Yb, t2s, out);
}

// Round 3
// 664.306 us; speedup vs baseline: 1.1473x; 1.0295x over previous
//
#include <hip/hip_runtime.h>
#include <hip/hip_bf16.h>

typedef __attribute__((ext_vector_type(8))) __bf16 bf16x8;
typedef __attribute__((ext_vector_type(4))) float floatx4;

constexpr int N_TOK = 4096;   // B*T
constexpr int DDIM  = 1024;
constexpr int FDIM  = 4096;
constexpr int NEXP  = 8;
constexpr int NSLOT = 2 * N_TOK; // 8192 assignments (top-2)
constexpr int BM_T  = 128;       // M tile
constexpr int MAXT  = NSLOT / BM_T + NEXP - 1; // 71 max M-tiles at BM=128
constexpr int KSPLIT = 2;        // down-GEMM K split

static __device__ __forceinline__ unsigned short f2bf(float f) {
    union { __hip_bfloat16 h; unsigned short u; } v;
    v.h = __float2bfloat16(f);
    return v.u;
}

// async 16B global->LDS DMA. LDS dest = wave-uniform base + lane*16 (m104/m108).
static __device__ __forceinline__ void gl2lds16(const unsigned short* g, unsigned short* l) {
    __builtin_amdgcn_global_load_lds(
        (__attribute__((address_space(1))) void*)g,
        (__attribute__((address_space(3))) void*)l,
        16, 0, 0);
}

// ---------------- fused W1+W2 fp32 -> bf16 cast (+ counts init) ----------------
__global__ void castW_kernel(const float* __restrict__ W1, const float* __restrict__ W2,
                             unsigned short* __restrict__ w1b, unsigned short* __restrict__ w2b,
                             int* __restrict__ counts) {
    constexpr int HALF = NEXP * FDIM * DDIM / 4; // float4 groups per tensor
    int i = blockIdx.x * 256 + threadIdx.x;
    const float* s; unsigned short* d; int j;
    if (i < HALF) { s = W1; d = w1b; j = i; }
    else          { s = W2; d = w2b; j = i - HALF; }
    float4 v = *(const float4*)(s + (size_t)j * 4);
    ushort4 o;
    o.x = f2bf(v.x); o.y = f2bf(v.y); o.z = f2bf(v.z); o.w = f2bf(v.w);
    *(ushort4*)(d + (size_t)j * 4) = o;
    if (blockIdx.x == 0 && threadIdx.x < NEXP) counts[threadIdx.x] = 0;
}

// ---------------- router: logits -> top2 -> weights; also emits xb ----------------
__global__ void router_kernel(const float* __restrict__ x, const float* __restrict__ Wr,
                              unsigned short* __restrict__ xb,
                              int* __restrict__ te, float* __restrict__ tw,
                              int* __restrict__ counts) {
    __shared__ float wr[NEXP * DDIM]; // 32 KB
    const int tid = threadIdx.x;
    for (int i = tid; i < NEXP * DDIM; i += 256) wr[i] = Wr[i];
    __syncthreads();
    const int wave = tid >> 6, lane = tid & 63;
    const int t = blockIdx.x * 4 + wave;

    float xr[16];
    const float* xp = x + (size_t)t * DDIM;
    #pragma unroll
    for (int i = 0; i < 16; i++) xr[i] = xp[lane + 64 * i];

    // fused x -> bf16 cast (same row already in registers)
    unsigned short* xbp = xb + (size_t)t * DDIM;
    #pragma unroll
    for (int i = 0; i < 16; i++) xbp[lane + 64 * i] = f2bf(xr[i]);

    float logit[NEXP];
    #pragma unroll
    for (int e = 0; e < NEXP; e++) {
        float s = 0.f;
        #pragma unroll
        for (int i = 0; i < 16; i++) s += xr[i] * wr[e * DDIM + lane + 64 * i];
        #pragma unroll
        for (int off = 32; off > 0; off >>= 1) s += __shfl_xor(s, off, 64);
        logit[e] = s;
    }
    if (lane == 0) {
        int i0 = 0; float l0 = logit[0];
        #pragma unroll
        for (int e = 1; e < NEXP; e++) if (logit[e] > l0) { l0 = logit[e]; i0 = e; }
        int i1 = -1; float l1 = -3.0e38f;
        #pragma unroll
        for (int e = 0; e < NEXP; e++) if (e != i0 && logit[e] > l1) { l1 = logit[e]; i1 = e; }
        float p1 = expf(l1 - l0);
        float w0 = 1.f / (1.f + p1);
        float w1 = p1 * w0;
        te[t * 2] = i0; te[t * 2 + 1] = i1;
        tw[t * 2] = w0; tw[t * 2 + 1] = w1;
        atomicAdd(&counts[i0], 1);
        atomicAdd(&counts[i1], 1);
    }
}

// ---------------- fused scan + tile table + scatter (single block) ----------------
__global__ void scan_scatter_kernel(const int* __restrict__ counts,
                                    const int* __restrict__ te, const float* __restrict__ tw,
                                    int* __restrict__ offsets, int* __restrict__ tile_em,
                                    int* __restrict__ ntile,
                                    int* __restrict__ rowid, float* __restrict__ gate,
                                    int* __restrict__ tok2slot) {
    __shared__ int soff[NEXP];
    __shared__ int scur[NEXP];
    const int tid = threadIdx.x;
    if (tid == 0) {
        int acc = 0, nt = 0;
        for (int e = 0; e < NEXP; e++) {
            offsets[e] = acc; soff[e] = acc;
            for (int m0 = 0; m0 < counts[e]; m0 += BM_T)
                tile_em[nt++] = (e << 16) | (m0 >> 7);
            acc += counts[e];
        }
        offsets[NEXP] = acc;
        ntile[0] = nt;
        for (int i = nt; i < MAXT; i++) tile_em[i] = 0;
    }
    if (tid < NEXP) scur[tid] = 0;
    __syncthreads();
    for (int t = tid; t < N_TOK; t += 256) {
        #pragma unroll
        for (int k = 0; k < 2; k++) {
            int e = te[t * 2 + k];
            int pos = atomicAdd(&scur[e], 1);
            int slot = soff[e] + pos;
            rowid[slot] = t;
            gate[slot] = tw[t * 2 + k];
            tok2slot[t * 2 + k] = slot;
        }
    }
}

// ---------------- grouped GEMM: BM=128 BN=128 BK=32, 4 waves, depth-3 pipeline ----------------
// Round-3 structure (T4, m218-mechanism): 3 LDS buffers; stage(t+2) issued at iter t;
// per-iter "s_waitcnt vmcnt(4) lgkmcnt(0); s_barrier" -- vmcnt NEVER drained to 0 in the
// main loop, so each stage has a ~2-iteration latency window, on top of 3 blocks/CU TLP
// (48 KB LDS, 256 thr). Swizzle fixed for 64B rows: s(r) = (r>>1)&3 on source AND read
// (round-2's r&3 was the wrong conflict axis -> 4-way; this gives 2 lanes/slot = free).
template <bool UP>
__global__ __launch_bounds__(256, 3)
void ffn_gemm(const unsigned short* __restrict__ A,
              const unsigned short* __restrict__ Wb,
              unsigned short* __restrict__ Hout,
              float* __restrict__ Y,
              const int* __restrict__ rowid,
              const float* __restrict__ gate,
              const int* __restrict__ offsets,
              const int* __restrict__ tile_em,
              const int* __restrict__ ntile) {
    constexpr int BM = 128, BN = 128, BK = 32;
    constexpr int NOUT = UP ? FDIM : DDIM;
    constexpr int KDIM = UP ? DDIM : FDIM;
    constexpr int NN   = NOUT / BN;                   // 32 / 8
    constexpr int KLEN = UP ? DDIM : (FDIM / KSPLIT); // 1024 / 2048
    constexpr int KT   = KLEN / BK;                   // 32 / 64
    constexpr int MREP = 4, NREP = 4;                 // 64x64 wave tile, 2Mx2N waves
    constexpr int ASTRIDE = BM * BK;                  // 4096 shorts = 8 KB / buffer
    constexpr int BSTRIDE = BN * BK;                  // 8 KB / buffer

    // bijective XCD-chunked swizzle (m204)
    const int nwg = NN * MAXT * (UP ? 1 : KSPLIT);    // == gridDim.x
    const int orig = blockIdx.x;
    const int xcd = orig & 7, idx = orig >> 3;
    const int qq = nwg >> 3, rr8 = nwg & 7;
    const int id = (xcd < rr8 ? xcd * (qq + 1) : rr8 * (qq + 1) + (xcd - rr8) * qq) + idx;

    const int n0 = (id % NN) * BN;                    // n fastest: neighbors share A tile
    const int bt = (id / NN) % MAXT;
    const int ks = UP ? 0 : (id / (NN * MAXT));
    if (bt >= ntile[0]) return;
    const int em = tile_em[bt];
    const int e  = em >> 16;
    const int m0 = (em & 0xffff) << 7;
    const int seg = offsets[e];
    const int cnt = offsets[e + 1] - seg;
    const int kbase = ks * KLEN;

    __shared__ __align__(16) unsigned short As[3 * ASTRIDE]; // 24 KB
    __shared__ __align__(16) unsigned short Bs[3 * BSTRIDE]; // 24 KB

    const int tid  = threadIdx.x;
    const int lane = tid & 63;
    const int wave = tid >> 6;
    const int lrow = lane >> 2;                       // 0..15: row within 16-row DMA group
    const int chunk = lane & 3;                       // 16B chunk within 64B row
    const int scol = (chunk ^ ((lrow >> 1) & 3)) * 8; // inverse-swizzled SOURCE col (shorts)

    // global source pointers (advance by BK shorts per staged tile)
    const unsigned short* ag[2];
    #pragma unroll
    for (int j = 0; j < 2; j++) {
        int arow = wave * 32 + j * 16 + lrow;
        int slot = seg + m0 + arow;
        if (slot >= NSLOT) slot = NSLOT - 1;          // clamp; write-guarded later
        if (UP) { int t = rowid[slot]; ag[j] = A + (size_t)t * DDIM + kbase + scol; }
        else    { ag[j] = A + (size_t)slot * FDIM + kbase + scol; }
    }
    const unsigned short* bg[2];
    #pragma unroll
    for (int j = 0; j < 2; j++) {
        int brow = wave * 32 + j * 16 + lrow;
        bg[j] = Wb + ((size_t)e * NOUT + n0 + brow) * KDIM + kbase + scol;
    }
    // linear LDS dests (gl2lds requirement): base + lane*16B
    unsigned short* asl[2];
    unsigned short* bsl[2];
    #pragma unroll
    for (int j = 0; j < 2; j++) {
        asl[j] = &As[(wave * 32 + j * 16) * BK] + lane * 8;
        bsl[j] = &Bs[(wave * 32 + j * 16) * BK] + lane * 8;
    }

    auto stage = [&](int b) {                         // 4 gl2lds per thread -> vmcnt unit = 4
        gl2lds16(ag[0], asl[0] + b * ASTRIDE); ag[0] += BK;
        gl2lds16(ag[1], asl[1] + b * ASTRIDE); ag[1] += BK;
        gl2lds16(bg[0], bsl[0] + b * BSTRIDE); bg[0] += BK;
        gl2lds16(bg[1], bsl[1] + b * BSTRIDE); bg[1] += BK;
    };

    const int frow = lane & 15;
    const int quad = lane >> 4;
    const int wm = (wave >> 1) * 64;                  // 2 wave-rows
    const int wn = (wave & 1) * 64;                   // 2 wave-cols
    const int cs = (quad ^ ((frow >> 1) & 3)) * 8;    // read-side swizzle (shorts)

    floatx4 acc[MREP][NREP];
    #pragma unroll
    for (int i = 0; i < MREP; i++)
        #pragma unroll
        for (int j = 0; j < NREP; j++)
            acc[i][j] = (floatx4){0.f, 0.f, 0.f, 0.f};

    // prologue: fill pipeline 2 deep; confirm stage(0) only (vmcnt(4) leaves stage(1) flying)
    stage(0);
    stage(1);
    asm volatile("s_waitcnt vmcnt(4)" ::: "memory");
    __builtin_amdgcn_s_barrier();
    __builtin_amdgcn_sched_barrier(0);

    int bc = 0, bs = 2;                               // compute buffer, stage buffer
    for (int t = 0; t < KT; ++t) {
        const bool more = (t + 2 < KT);
        if (more) stage(bs);
        const unsigned short* Ab = &As[bc * ASTRIDE];
        const unsigned short* Bb = &Bs[bc * BSTRIDE];
        bf16x8 av[MREP], bv[NREP];
        #pragma unroll
        for (int i = 0; i < MREP; i++)
            av[i] = *(const bf16x8*)&Ab[(wm + i * 16 + frow) * BK + cs];
        #pragma unroll
        for (int j = 0; j < NREP; j++)
            bv[j] = *(const bf16x8*)&Bb[(wn + j * 16 + frow) * BK + cs];
        __builtin_amdgcn_s_setprio(1);
        #pragma unroll
        for (int i = 0; i < MREP; i++)
            #pragma unroll
            for (int j = 0; j < NREP; j++)
                acc[i][j] = __builtin_amdgcn_mfma_f32_16x16x32_bf16(av[i], bv[j], acc[i][j], 0, 0, 0);
        __builtin_amdgcn_s_setprio(0);
        // counted wait: stage(t+1) confirmed landed (own); stage(t+2) stays in flight.
        // lgkmcnt(0): my ds_reads done -> safe for anyone to overwrite buf read this iter.
        if (more) asm volatile("s_waitcnt vmcnt(4) lgkmcnt(0)" ::: "memory");
        else      asm volatile("s_waitcnt vmcnt(0) lgkmcnt(0)" ::: "memory");
        if (t < KT - 1) {
            __builtin_amdgcn_s_barrier();
            __builtin_amdgcn_sched_barrier(0);
        }
        bc = (bc == 2) ? 0 : bc + 1;
        bs = (bs == 2) ? 0 : bs + 1;
    }

    // epilogue: C/D layout col=lane&15, row=quad*4+reg (m89/m91-verified)
    #pragma unroll
    for (int mt = 0; mt < MREP; mt++) {
        #pragma unroll
        for (int rg = 0; rg < 4; rg++) {
            int mloc = m0 + wm + mt * 16 + quad * 4 + rg;
            if (mloc >= cnt) continue;                // write-guard
            int slot = seg + mloc;
            if (UP) {
                #pragma unroll
                for (int nt = 0; nt < NREP; nt++) {
                    int n = n0 + wn + nt * 16 + frow;
                    float v = acc[mt][nt][rg];
                    float g = 0.5f * v * (1.0f + erff(v * 0.70710678118654752f)); // exact gelu
                    Hout[(size_t)slot * FDIM + n] = f2bf(g);
                }
            } else {
                float gw = gate[slot];
                #pragma unroll
                for (int nt = 0; nt < NREP; nt++) {
                    int n = n0 + wn + nt * 16 + frow;
                    Y[((size_t)ks * NSLOT + slot) * DDIM + n] = gw * acc[mt][nt][rg];
                }
            }
        }
    }
}

// ---------------- combine: out[t] = sum over ks slabs of Y[slot0]+Y[slot1] ----------------
__global__ void combine_kernel(const float* __restrict__ Y, const int* __restrict__ tok2slot,
                               float* __restrict__ out) {
    int idx = blockIdx.x * 256 + threadIdx.x;
    int t = idx >> 8;
    int c = (idx & 255) * 4;
    int s0 = tok2slot[t * 2], s1 = tok2slot[t * 2 + 1];
    float4 r = make_float4(0.f, 0.f, 0.f, 0.f);
    #pragma unroll
    for (int ks = 0; ks < KSPLIT; ks++) {
        float4 a = *(const float4*)(Y + ((size_t)ks * NSLOT + s0) * DDIM + c);
        float4 b = *(const float4*)(Y + ((size_t)ks * NSLOT + s1) * DDIM + c);
        r.x += a.x + b.x; r.y += a.y + b.y; r.z += a.z + b.z; r.w += a.w + b.w;
    }
    *(float4*)(out + (size_t)t * DDIM + c) = r;
}

extern "C" void kernel_launch(void* const* d_in, const int* in_sizes, int n_in,
                              void* d_out, int out_size, void* d_ws, size_t ws_size,
                              hipStream_t stream) {
    const float* x  = (const float*)d_in[0];
    const float* Wr = (const float*)d_in[1];
    const float* W1 = (const float*)d_in[2];
    const float* W2 = (const float*)d_in[3];
    float* out = (float*)d_out;

    char* ws = (char*)d_ws;
    size_t off = 0;
    auto alloc = [&](size_t bytes) -> char* {
        char* p = ws + off;
        off = (off + bytes + 255) & ~(size_t)255;
        return p;
    };
    unsigned short* xb   = (unsigned short*)alloc((size_t)N_TOK * DDIM * 2);
    unsigned short* H    = (unsigned short*)alloc((size_t)NSLOT * FDIM * 2);
    float* Yb      = (float*)alloc((size_t)KSPLIT * NSLOT * DDIM * 4);
    int*   rowid   = (int*)alloc(NSLOT * 4);
    float* gatew   = (float*)alloc(NSLOT * 4);
    int*   te      = (int*)alloc(NSLOT * 4);
    float* tw      = (float*)alloc(NSLOT * 4);
    int*   t2s     = (int*)alloc(NSLOT * 4);
    int*   counts  = (int*)alloc(64);
    int*   offsets = (int*)alloc(64);
    int*   tile_em = (int*)alloc(MAXT * 4);
    int*   ntile   = (int*)alloc(64);
    unsigned short* w1b = (unsigned short*)alloc((size_t)NEXP * FDIM * DDIM * 2);
    unsigned short* w2b = (unsigned short*)alloc((size_t)NEXP * DDIM * FDIM * 2);
    (void)ws_size;

    constexpr int GRID_UP = (FDIM / 128) * MAXT;           // 2272 blocks
    constexpr int GRID_DN = (DDIM / 128) * MAXT * KSPLIT;  // 1136 blocks

    castW_kernel<<<2 * NEXP * FDIM * DDIM / 4 / 256, 256, 0, stream>>>(W1, W2, w1b, w2b, counts);
    router_kernel<<<N_TOK / 4, 256, 0, stream>>>(x, Wr, xb, te, tw, counts);
    scan_scatter_kernel<<<1, 256, 0, stream>>>(counts, te, tw, offsets, tile_em, ntile,
                                               rowid, gatew, t2s);
    ffn_gemm<true ><<<GRID_UP, 256, 0, stream>>>(xb, w1b, H, Yb, rowid, gatew,
                                                 offsets, tile_em, ntile);
    ffn_gemm<false><<<GRID_DN, 256, 0, stream>>>(H, w2b, H, Yb, rowid, gatew,
                                                 offsets, tile_em, ntile);
    combine_kernel<<<N_TOK, 256, 0, stream>>>(Yb, t2s, out);
}